// Round 1
// baseline (157.081 us; speedup 1.0000x reference)
//
#include <hip/hip_runtime.h>

#define NB 4
#define NQ 128
#define NK 1024
#define NH 256
#define NE 256
#define NV 256

#define TSCALE 2.8853900817779268f  // 2*log2(e): pre-scale so exp2(qs+ks) = e^{2(qp+kp)}
#define LOG2E  1.4426950408889634f

static __device__ __forceinline__ float fexp2(float x){ return __builtin_amdgcn_exp2f(x); }
static __device__ __forceinline__ float frcp (float x){ return __builtin_amdgcn_rcpf(x); }

// ---------------- proj_q: qs[b*NQ+q][h] = TSCALE * sum_e queries[row][e]*Wq[e][h]
// 512 rows / 4 rows-per-block = 128 blocks x 256 threads (thread = h)
__global__ __launch_bounds__(256) void proj_q_kernel(const float* __restrict__ qin,
                                                     const float* __restrict__ Wq,
                                                     float* __restrict__ qs) {
    const int tid  = threadIdx.x;
    const int row0 = blockIdx.x * 4;
    const float* r0 = qin + (row0 + 0) * NE;
    const float* r1 = qin + (row0 + 1) * NE;
    const float* r2 = qin + (row0 + 2) * NE;
    const float* r3 = qin + (row0 + 3) * NE;
    float a0 = 0.f, a1 = 0.f, a2 = 0.f, a3 = 0.f;
#pragma unroll 8
    for (int e = 0; e < NE; ++e) {
        float w = Wq[e * NH + tid];          // coalesced
        a0 = fmaf(r0[e], w, a0);             // uniform (scalar) loads
        a1 = fmaf(r1[e], w, a1);
        a2 = fmaf(r2[e], w, a2);
        a3 = fmaf(r3[e], w, a3);
    }
    qs[(row0 + 0) * NH + tid] = a0 * TSCALE;
    qs[(row0 + 1) * NH + tid] = a1 * TSCALE;
    qs[(row0 + 2) * NH + tid] = a2 * TSCALE;
    qs[(row0 + 3) * NH + tid] = a3 * TSCALE;
}

// ---------------- proj_k: kT[b][h][k] = TSCALE * sum_e keys[b*NK+k][e]*Wk[e][h]
// 4096 rows / 8 = 512 blocks x 256 threads (thread = h); LDS transpose for coalesced stores
__global__ __launch_bounds__(256) void proj_k_kernel(const float* __restrict__ kin,
                                                     const float* __restrict__ Wk,
                                                     float* __restrict__ kT) {
    const int tid  = threadIdx.x;
    const int row0 = blockIdx.x * 8;         // 8 | 1024 so a block never crosses b
    const int b    = row0 >> 10;
    const int k0   = row0 & (NK - 1);
    float acc[8] = {0.f,0.f,0.f,0.f,0.f,0.f,0.f,0.f};
#pragma unroll 4
    for (int e = 0; e < NE; ++e) {
        float w = Wk[e * NH + tid];
#pragma unroll
        for (int i = 0; i < 8; ++i)
            acc[i] = fmaf(kin[(row0 + i) * NE + e], w, acc[i]);
    }
    __shared__ __align__(16) float tr[NH][9];
#pragma unroll
    for (int i = 0; i < 8; ++i) tr[tid][i] = acc[i] * TSCALE;
    __syncthreads();
#pragma unroll
    for (int p = 0; p < 2; ++p) {
        int h  = p * 128 + (tid >> 1);
        int kk = (tid & 1) * 4;
        float4 v = make_float4(tr[h][kk], tr[h][kk + 1], tr[h][kk + 2], tr[h][kk + 3]);
        *(float4*)(&kT[b * NH * NK + h * NK + k0 + kk]) = v;  // 16B-aligned, 32B/h-row
    }
}

// ---------------- scores: sc[b][q][k] = sum_h Wv[h]*tanh-like, two q rows per block,
// one 256-wide k-chunk per block; early-exit on fully-masked chunks (load balance).
// grid = 1024: bits [9:8]=chunk, [7:3]=qp-hi, [2:1]=b (XCD locality), [0]=qp-lo
__global__ __launch_bounds__(256) void scores_kernel(const float* __restrict__ qs,
                                                     const float* __restrict__ kT,
                                                     const int* __restrict__ vlen,
                                                     const float* __restrict__ Wv,
                                                     float* __restrict__ sc_out) {
    const int tid   = threadIdx.x;
    const int idx   = blockIdx.x;
    const int b     = (idx & 7) >> 1;
    const int chunk = idx >> 8;
    const int qp    = (((idx >> 3) & 31) << 1) | (idx & 1);
    const int q0    = qp * 2;
    const int vl    = vlen[b];
    if (chunk * 256 >= vl) return;           // whole chunk masked -> no work

    __shared__ __align__(16) float qv0[NH];
    __shared__ __align__(16) float dd[NH];   // exp2(q1[h]-q0[h])
    __shared__ __align__(16) float wv_s[NH];
    __shared__ float redw[4];

    float w = Wv[tid];
    wv_s[tid] = w;
    float qa = qs[(b * NQ + q0) * NH + tid];
    float qb = qs[(b * NQ + q0 + 1) * NH + tid];
    qv0[tid] = qa;
    dd[tid]  = fexp2(qb - qa);
    float ssum = w;
#pragma unroll
    for (int m = 32; m >= 1; m >>= 1) ssum += __shfl_xor(ssum, m, 64);
    if ((tid & 63) == 0) redw[tid >> 6] = ssum;
    __syncthreads();
    const float wvsum = redw[0] + redw[1] + redw[2] + redw[3];

    const int k = chunk * 256 + tid;
    const float* kp = kT + b * NH * NK + k;
    float a0 = 0.f, a1 = 0.f;
#pragma unroll 8
    for (int h = 0; h < NH; ++h) {
        float kv  = kp[h * NK];              // coalesced 256B/wave
        float t0  = fexp2(qv0[h] + kv);      // e^{2(qp0+kp)}
        float t1  = t0 * dd[h];              // e^{2(qp1+kp)} -- saves one exp2
        float wvh = wv_s[h];
        a0 = fmaf(wvh, frcp(t0 + 1.0f), a0); // tanh = 1 - 2*rcp(t+1); fold the "1" into wvsum
        a1 = fmaf(wvh, frcp(t1 + 1.0f), a1);
    }
    sc_out[(b * NQ + q0) * NK + k]     = wvsum - 2.0f * a0;
    sc_out[(b * NQ + q0 + 1) * NK + k] = wvsum - 2.0f * a1;
}

// ---------------- softpv: masked softmax over k (<vl) + attn@V, two q rows per block
// grid = 256: [7:3]+[0] -> qp, [2:1] -> b
__global__ __launch_bounds__(256) void softpv_kernel(const float* __restrict__ sc_in,
                                                     const float* __restrict__ V,
                                                     const int* __restrict__ vlen,
                                                     float* __restrict__ out) {
    const int tid  = threadIdx.x;
    const int lane = tid & 63;
    const int wid  = tid >> 6;
    const int idx  = blockIdx.x;
    const int b    = (idx & 7) >> 1;
    const int qp   = ((idx >> 3) << 1) | (idx & 1);
    const int q0   = qp * 2;
    const int vl   = vlen[b];

    __shared__ __align__(16) float attnw[2][NK];
    __shared__ float redm[4][2];
    __shared__ float reds[4][2];
    __shared__ __align__(16) float pvred[4][64][8];

    const float* s0p = sc_in + (b * NQ + q0) * NK;
    const float* s1p = s0p + NK;

    float sc0[4], sc1[4];
    float m0 = -1e30f, m1 = -1e30f;
#pragma unroll
    for (int c = 0; c < 4; ++c) {
        int k = c * 256 + tid;
        bool ok = k < vl;
        sc0[c] = ok ? s0p[k] : -1e30f;
        sc1[c] = ok ? s1p[k] : -1e30f;
        m0 = fmaxf(m0, sc0[c]);
        m1 = fmaxf(m1, sc1[c]);
    }
#pragma unroll
    for (int m = 32; m >= 1; m >>= 1) {
        m0 = fmaxf(m0, __shfl_xor(m0, m, 64));
        m1 = fmaxf(m1, __shfl_xor(m1, m, 64));
    }
    if (lane == 0) { redm[wid][0] = m0; redm[wid][1] = m1; }
    __syncthreads();
    m0 = fmaxf(fmaxf(redm[0][0], redm[1][0]), fmaxf(redm[2][0], redm[3][0]));
    m1 = fmaxf(fmaxf(redm[0][1], redm[1][1]), fmaxf(redm[2][1], redm[3][1]));

    float su0 = 0.f, su1 = 0.f;
#pragma unroll
    for (int c = 0; c < 4; ++c) {
        sc0[c] = fexp2((sc0[c] - m0) * LOG2E);  // masked -> exp2(-huge) = 0 exactly
        sc1[c] = fexp2((sc1[c] - m1) * LOG2E);
        su0 += sc0[c];
        su1 += sc1[c];
    }
#pragma unroll
    for (int m = 32; m >= 1; m >>= 1) {
        su0 += __shfl_xor(su0, m, 64);
        su1 += __shfl_xor(su1, m, 64);
    }
    if (lane == 0) { reds[wid][0] = su0; reds[wid][1] = su1; }
    __syncthreads();
    su0 = reds[0][0] + reds[1][0] + reds[2][0] + reds[3][0];
    su1 = reds[0][1] + reds[1][1] + reds[2][1] + reds[3][1];
    const float i0 = frcp(su0), i1 = frcp(su1);
#pragma unroll
    for (int c = 0; c < 4; ++c) {
        attnw[0][c * 256 + tid] = sc0[c] * i0;
        attnw[1][c * 256 + tid] = sc1[c] * i1;
    }
    __syncthreads();

    // PV: thread = (kofs = wid, v4 = (lane)*4); float4 V loads, attn broadcast
    const int v4 = lane << 2;
    const float* Vb = V + b * NK * NV;
    const int kmax = (vl + 15) & ~15;
    float x0 = 0.f, x1 = 0.f, x2 = 0.f, x3 = 0.f;
    float y0 = 0.f, y1 = 0.f, y2 = 0.f, y3 = 0.f;
    for (int k0 = wid * 4; k0 < kmax; k0 += 16) {
        float4 aw0 = *(const float4*)&attnw[0][k0];
        float4 aw1 = *(const float4*)&attnw[1][k0];
#pragma unroll
        for (int j = 0; j < 4; ++j) {
            float4 vv = *(const float4*)&Vb[(k0 + j) * NV + v4];
            float aj0 = (j == 0) ? aw0.x : (j == 1) ? aw0.y : (j == 2) ? aw0.z : aw0.w;
            float aj1 = (j == 0) ? aw1.x : (j == 1) ? aw1.y : (j == 2) ? aw1.z : aw1.w;
            x0 = fmaf(aj0, vv.x, x0); x1 = fmaf(aj0, vv.y, x1);
            x2 = fmaf(aj0, vv.z, x2); x3 = fmaf(aj0, vv.w, x3);
            y0 = fmaf(aj1, vv.x, y0); y1 = fmaf(aj1, vv.y, y1);
            y2 = fmaf(aj1, vv.z, y2); y3 = fmaf(aj1, vv.w, y3);
        }
    }
    *(float4*)&pvred[wid][lane][0] = make_float4(x0, x1, x2, x3);
    *(float4*)&pvred[wid][lane][4] = make_float4(y0, y1, y2, y3);
    __syncthreads();
    if (tid < 128) {
        int qq = tid >> 6;
        int vs = tid & 63;
        float4 r = make_float4(0.f, 0.f, 0.f, 0.f);
#pragma unroll
        for (int ko = 0; ko < 4; ++ko) {
            float4 t = *(const float4*)&pvred[ko][vs][qq * 4];
            r.x += t.x; r.y += t.y; r.z += t.z; r.w += t.w;
        }
        *(float4*)&out[(b * NQ + q0 + qq) * NV + (vs << 2)] = r;
    }
}

extern "C" void kernel_launch(void* const* d_in, const int* in_sizes, int n_in,
                              void* d_out, int out_size, void* d_ws, size_t ws_size,
                              hipStream_t stream) {
    const float* queries = (const float*)d_in[0];
    const float* keys    = (const float*)d_in[1];
    const float* values  = (const float*)d_in[2];
    const int*   vlens   = (const int*)  d_in[3];
    const float* Wq      = (const float*)d_in[4];
    const float* Wk      = (const float*)d_in[5];
    const float* Wv      = (const float*)d_in[6];
    float* out = (float*)d_out;

    float* qs = (float*)d_ws;                      // 4*128*256  = 131072 floats (512 KB)
    float* kT = qs + NB * NQ * NH;                 // 4*256*1024 = 1M floats (4 MB)
    float* sc = kT + NB * NH * NK;                 // 4*128*1024 = 512K floats (2 MB)

    proj_q_kernel<<<dim3(NB * NQ / 4), dim3(256), 0, stream>>>(queries, Wq, qs);
    proj_k_kernel<<<dim3(NB * NK / 8), dim3(256), 0, stream>>>(keys, Wk, kT);
    scores_kernel<<<dim3(1024), dim3(256), 0, stream>>>(qs, kT, vlens, Wv, sc);
    softpv_kernel<<<dim3(256), dim3(256), 0, stream>>>(sc, values, vlens, out);
}

// Round 2
// 133.235 us; speedup vs baseline: 1.1790x; 1.1790x over previous
//
#include <hip/hip_runtime.h>

#define NB 4
#define NQ 128
#define NK 1024
#define NH 256
#define NE 256
#define NV 256

#define TSCALE 2.8853900817779268f  // 2*log2(e)
#define LOG2E  1.4426950408889634f

static __device__ __forceinline__ float fexp2(float x){ return __builtin_amdgcn_exp2f(x); }
static __device__ __forceinline__ float frcp (float x){ return __builtin_amdgcn_rcpf(x); }
static __device__ __forceinline__ float tanh_of(float x){
    // tanh(x) = 1 - 2/(e^{2x}+1), e^{2x} = exp2(x*TSCALE); safe at +-inf
    float e = fexp2(x * TSCALE);
    return fmaf(-2.0f, frcp(e + 1.0f), 1.0f);
}

// ---------------- proj: blocks [0,128): q-side (4 rows each) -> qdatA/qdatB packed
//                        blocks [128,640): k-side (8 rows each) -> kT4 h-interleaved
// qdatA[(b*32+qq)*256+h] = (Ta_r0, wv*Ta_r0, Ta_r1, wv*Ta_r1); qdatB same for rows 2,3
// kT4[(b*64+hg)*1024+k]  = (Tb[4hg][k], Tb[4hg+1][k], Tb[4hg+2][k], Tb[4hg+3][k])
__global__ __launch_bounds__(256) void proj_kernel(
    const float* __restrict__ qin, const float* __restrict__ kin,
    const float* __restrict__ Wq, const float* __restrict__ Wk,
    const float* __restrict__ Wv,
    float4* __restrict__ qdatA, float4* __restrict__ qdatB,
    float4* __restrict__ kT4) {
    const int tid = threadIdx.x;
    const int bi  = blockIdx.x;
    __shared__ float tr[NH][9];
    if (bi < NB * 32) {
        const int row0 = bi * 4;
        const float* r0 = qin + row0 * NE;
        float a0 = 0.f, a1 = 0.f, a2 = 0.f, a3 = 0.f;
#pragma unroll 2
        for (int e = 0; e < NE; e += 4) {
            float4 q0 = *(const float4*)(r0 + e);
            float4 q1 = *(const float4*)(r0 + NE + e);
            float4 q2 = *(const float4*)(r0 + 2 * NE + e);
            float4 q3 = *(const float4*)(r0 + 3 * NE + e);
#pragma unroll
            for (int j = 0; j < 4; ++j) {
                float w = Wq[(e + j) * NH + tid];   // coalesced
                a0 = fmaf(((const float*)&q0)[j], w, a0);
                a1 = fmaf(((const float*)&q1)[j], w, a1);
                a2 = fmaf(((const float*)&q2)[j], w, a2);
                a3 = fmaf(((const float*)&q3)[j], w, a3);
            }
        }
        float wv = Wv[tid];
        float t0 = tanh_of(a0), t1 = tanh_of(a1), t2 = tanh_of(a2), t3 = tanh_of(a3);
        qdatA[bi * NH + tid] = make_float4(t0, wv * t0, t1, wv * t1);
        qdatB[bi * NH + tid] = make_float4(t2, wv * t2, t3, wv * t3);
    } else {
        const int kb = bi - NB * 32;
        const int b  = kb >> 7;
        const int k0 = (kb & 127) * 8;
        const float* kr = kin + (b * NK + k0) * NE;
        float acc[8] = {0.f,0.f,0.f,0.f,0.f,0.f,0.f,0.f};
#pragma unroll 2
        for (int e = 0; e < NE; e += 4) {
            float4 kvv[8];
#pragma unroll
            for (int i = 0; i < 8; ++i) kvv[i] = *(const float4*)(kr + i * NE + e);
#pragma unroll
            for (int j = 0; j < 4; ++j) {
                float w = Wk[(e + j) * NH + tid];   // coalesced
#pragma unroll
                for (int i = 0; i < 8; ++i)
                    acc[i] = fmaf(((const float*)&kvv[i])[j], w, acc[i]);
            }
        }
#pragma unroll
        for (int i = 0; i < 8; ++i) tr[tid][i] = tanh_of(acc[i]);
        __syncthreads();
#pragma unroll
        for (int p = 0; p < 2; ++p) {
            int idx2 = p * 256 + tid;
            int hg = idx2 >> 3;
            int kk = idx2 & 7;
            float4 v = make_float4(tr[hg*4+0][kk], tr[hg*4+1][kk],
                                   tr[hg*4+2][kk], tr[hg*4+3][kk]);
            kT4[(b * 64 + hg) * NK + k0 + kk] = v;
        }
    }
}

// ---------------- fused attention: one 256-wide k-chunk per block, 4 q-rows.
// grid 512: bi = qq*16 + b*4 + quarter (same (b,quarter) -> same XCD for kT/V L2 reuse)
// Emits per-chunk softmax partials (m, s, pv) for the combine kernel.
__global__ __launch_bounds__(256) void attn_kernel(
    const float4* __restrict__ qdatA, const float4* __restrict__ qdatB,
    const float4* __restrict__ kT4, const float* __restrict__ V,
    const int* __restrict__ vlen, const float* __restrict__ Wv,
    float* __restrict__ part_m, float* __restrict__ part_s,
    float* __restrict__ part_pv) {
    const int tid = threadIdx.x, lane = tid & 63, wid = tid >> 6;
    const int bi = blockIdx.x;
    const int quarter = bi & 3;
    const int b  = (bi >> 2) & 3;
    const int qq = bi >> 4;
    const int vl = vlen[b];
    const int nch = (vl + 255) >> 8;
    const int pidx = (b * 32 + qq) * 4 + quarter;
    float* pm  = part_m + pidx * 4;
    float* ps  = part_s + pidx * 4;
    float* ppv = part_pv + pidx * (4 * NV);

    if (quarter >= nch) {                      // fully-masked chunk: empty partial
        if (tid < 4) { pm[tid] = -1e30f; ps[tid] = 0.0f; }
#pragma unroll
        for (int i = 0; i < 4; ++i) ppv[i * 256 + tid] = 0.0f;
        return;
    }

    __shared__ float4 qshA[NH], qshB[NH];
    __shared__ float  wv_s[NH];
    __shared__ float  pw[4][NH];
    __shared__ float4 pvred[4][64][4];
    __shared__ float  red[4][8];

    qshA[tid] = qdatA[(b * 32 + qq) * NH + tid];
    qshB[tid] = qdatB[(b * 32 + qq) * NH + tid];
    wv_s[tid] = Wv[tid];
    __syncthreads();

    const int k = quarter * 256 + tid;
    const float4* kp = kT4 + (b * 64) * NK + k;
    float acc0 = 0.f, acc1 = 0.f, acc2 = 0.f, acc3 = 0.f;
#pragma unroll 4
    for (int h4 = 0; h4 < 64; ++h4) {
        float4 kv4 = kp[h4 * NK];                       // dwordx4, 1KB/wave
        float4 wv4 = *(const float4*)&wv_s[h4 * 4];     // one b128 per 4 h
#pragma unroll
        for (int j = 0; j < 4; ++j) {
            float kv  = ((const float*)&kv4)[j];
            float wvb = ((const float*)&wv4)[j] * kv;   // wv*Tb shared by 4 rows
            float4 qa = qshA[h4 * 4 + j];
            float4 qb = qshB[h4 * 4 + j];
            // wv*tanh(qp+kp) = (wv*Ta + wv*Tb) * rcp(1 + Ta*Tb)
            acc0 = fmaf(qa.y + wvb, frcp(fmaf(qa.x, kv, 1.0f)), acc0);
            acc1 = fmaf(qa.w + wvb, frcp(fmaf(qa.z, kv, 1.0f)), acc1);
            acc2 = fmaf(qb.y + wvb, frcp(fmaf(qb.x, kv, 1.0f)), acc2);
            acc3 = fmaf(qb.w + wvb, frcp(fmaf(qb.z, kv, 1.0f)), acc3);
        }
    }
    const bool okk = k < vl;
    float s0 = okk ? acc0 : -1e30f;
    float s1 = okk ? acc1 : -1e30f;
    float s2 = okk ? acc2 : -1e30f;
    float s3 = okk ? acc3 : -1e30f;
    float m0 = s0, m1 = s1, m2 = s2, m3 = s3;
#pragma unroll
    for (int d = 32; d >= 1; d >>= 1) {
        m0 = fmaxf(m0, __shfl_xor(m0, d, 64));
        m1 = fmaxf(m1, __shfl_xor(m1, d, 64));
        m2 = fmaxf(m2, __shfl_xor(m2, d, 64));
        m3 = fmaxf(m3, __shfl_xor(m3, d, 64));
    }
    if (lane == 0) { red[wid][0]=m0; red[wid][1]=m1; red[wid][2]=m2; red[wid][3]=m3; }
    __syncthreads();
    m0 = fmaxf(fmaxf(red[0][0], red[1][0]), fmaxf(red[2][0], red[3][0]));
    m1 = fmaxf(fmaxf(red[0][1], red[1][1]), fmaxf(red[2][1], red[3][1]));
    m2 = fmaxf(fmaxf(red[0][2], red[1][2]), fmaxf(red[2][2], red[3][2]));
    m3 = fmaxf(fmaxf(red[0][3], red[1][3]), fmaxf(red[2][3], red[3][3]));
    float p0 = fexp2((s0 - m0) * LOG2E);   // masked -> exactly 0
    float p1 = fexp2((s1 - m1) * LOG2E);
    float p2 = fexp2((s2 - m2) * LOG2E);
    float p3 = fexp2((s3 - m3) * LOG2E);
    pw[0][tid] = p0; pw[1][tid] = p1; pw[2][tid] = p2; pw[3][tid] = p3;
    float u0 = p0, u1 = p1, u2 = p2, u3 = p3;
#pragma unroll
    for (int d = 32; d >= 1; d >>= 1) {
        u0 += __shfl_xor(u0, d, 64); u1 += __shfl_xor(u1, d, 64);
        u2 += __shfl_xor(u2, d, 64); u3 += __shfl_xor(u3, d, 64);
    }
    if (lane == 0) { red[wid][4]=u0; red[wid][5]=u1; red[wid][6]=u2; red[wid][7]=u3; }
    __syncthreads();
    if (tid == 0) {
        pm[0] = m0; pm[1] = m1; pm[2] = m2; pm[3] = m3;
        ps[0] = red[0][4]+red[1][4]+red[2][4]+red[3][4];
        ps[1] = red[0][5]+red[1][5]+red[2][5]+red[3][5];
        ps[2] = red[0][6]+red[1][6]+red[2][6]+red[3][6];
        ps[3] = red[0][7]+red[1][7]+red[2][7]+red[3][7];
    }
    // PV over this chunk: wid picks k-offset group, lane picks v-float4
    const float* Vb = V + (b * NK + quarter * 256) * NV;
    const int v4 = lane * 4;
    float4 o0 = {0,0,0,0}, o1 = {0,0,0,0}, o2 = {0,0,0,0}, o3 = {0,0,0,0};
    for (int kk0 = wid * 4; kk0 < 256; kk0 += 16) {
        float4 pr0 = *(const float4*)&pw[0][kk0];
        float4 pr1 = *(const float4*)&pw[1][kk0];
        float4 pr2 = *(const float4*)&pw[2][kk0];
        float4 pr3 = *(const float4*)&pw[3][kk0];
#pragma unroll
        for (int j = 0; j < 4; ++j) {
            float4 vv = *(const float4*)&Vb[(kk0 + j) * NV + v4];
            float w0 = ((const float*)&pr0)[j], w1 = ((const float*)&pr1)[j];
            float w2 = ((const float*)&pr2)[j], w3 = ((const float*)&pr3)[j];
            o0.x = fmaf(w0, vv.x, o0.x); o0.y = fmaf(w0, vv.y, o0.y);
            o0.z = fmaf(w0, vv.z, o0.z); o0.w = fmaf(w0, vv.w, o0.w);
            o1.x = fmaf(w1, vv.x, o1.x); o1.y = fmaf(w1, vv.y, o1.y);
            o1.z = fmaf(w1, vv.z, o1.z); o1.w = fmaf(w1, vv.w, o1.w);
            o2.x = fmaf(w2, vv.x, o2.x); o2.y = fmaf(w2, vv.y, o2.y);
            o2.z = fmaf(w2, vv.z, o2.z); o2.w = fmaf(w2, vv.w, o2.w);
            o3.x = fmaf(w3, vv.x, o3.x); o3.y = fmaf(w3, vv.y, o3.y);
            o3.z = fmaf(w3, vv.z, o3.z); o3.w = fmaf(w3, vv.w, o3.w);
        }
    }
    pvred[wid][lane][0] = o0; pvred[wid][lane][1] = o1;
    pvred[wid][lane][2] = o2; pvred[wid][lane][3] = o3;
    __syncthreads();
    {
        int row = tid >> 6, vg = tid & 63;
        float4 r = {0,0,0,0};
#pragma unroll
        for (int w = 0; w < 4; ++w) {
            float4 t = pvred[w][vg][row];
            r.x += t.x; r.y += t.y; r.z += t.z; r.w += t.w;
        }
        *(float4*)&ppv[row * NV + vg * 4] = r;
    }
}

// ---------------- combine: merge 4 chunk partials per (b,qq), write out
__global__ __launch_bounds__(256) void combine_kernel(
    const float* __restrict__ part_m, const float* __restrict__ part_s,
    const float* __restrict__ part_pv, float* __restrict__ out) {
    const int tid = threadIdx.x;
    const int bi  = blockIdx.x;   // 0..127 = b*32+qq
    const int base = bi * 4;
#pragma unroll
    for (int i = 0; i < 4; ++i) {
        float m[4], s[4];
#pragma unroll
        for (int q = 0; q < 4; ++q) {
            m[q] = part_m[(base + q) * 4 + i];
            s[q] = part_s[(base + q) * 4 + i];
        }
        float M = fmaxf(fmaxf(m[0], m[1]), fmaxf(m[2], m[3]));
        float w[4], S = 0.f;
#pragma unroll
        for (int q = 0; q < 4; ++q) {
            w[q] = fexp2((m[q] - M) * LOG2E);   // empty partial -> 0
            S = fmaf(s[q], w[q], S);
        }
        float o = 0.f;
#pragma unroll
        for (int q = 0; q < 4; ++q)
            o = fmaf(part_pv[((base + q) * 4 + i) * NV + tid], w[q], o);
        out[(base + i) * NV + tid] = o * frcp(S);
    }
}

extern "C" void kernel_launch(void* const* d_in, const int* in_sizes, int n_in,
                              void* d_out, int out_size, void* d_ws, size_t ws_size,
                              hipStream_t stream) {
    const float* queries = (const float*)d_in[0];
    const float* keys    = (const float*)d_in[1];
    const float* values  = (const float*)d_in[2];
    const int*   vlens   = (const int*)  d_in[3];
    const float* Wq      = (const float*)d_in[4];
    const float* Wk      = (const float*)d_in[5];
    const float* Wv      = (const float*)d_in[6];
    float* out = (float*)d_out;

    float4* qdatA  = (float4*)d_ws;                  // 32768 float4 (512 KB)
    float4* qdatB  = qdatA + NB * 32 * NH;           // 32768 float4 (512 KB)
    float4* kT4    = qdatB + NB * 32 * NH;           // 262144 float4 (4 MB)
    float*  part_m = (float*)(kT4 + NB * 64 * NK);   // 2048 floats
    float*  part_s = part_m + 2048;                  // 2048 floats
    float*  part_pv = part_s + 2048;                 // 524288 floats (2 MB)

    proj_kernel   <<<dim3(640), dim3(256), 0, stream>>>(queries, keys, Wq, Wk, Wv,
                                                        qdatA, qdatB, kT4);
    attn_kernel   <<<dim3(512), dim3(256), 0, stream>>>(qdatA, qdatB, kT4, values,
                                                        vlens, Wv, part_m, part_s, part_pv);
    combine_kernel<<<dim3(128), dim3(256), 0, stream>>>(part_m, part_s, part_pv, out);
}

// Round 3
// 131.821 us; speedup vs baseline: 1.1916x; 1.0107x over previous
//
#include <hip/hip_runtime.h>

#define NB 4
#define NQ 128
#define NK 1024
#define NH 256
#define NE 256
#define NV 256

#define TSCALE 2.8853900817779268f  // 2*log2(e)
#define LOG2E  1.4426950408889634f

static __device__ __forceinline__ float fexp2(float x){ return __builtin_amdgcn_exp2f(x); }
static __device__ __forceinline__ float frcp (float x){ return __builtin_amdgcn_rcpf(x); }
static __device__ __forceinline__ float tanh_of(float x){
    float e = fexp2(x * TSCALE);
    return fmaf(-2.0f, frcp(e + 1.0f), 1.0f);
}

// ---------------- proj: blocks [0,128): q-side (4 rows each) -> qdatA/qdatB packed
//                        blocks [128,640): k-side (8 rows each) -> kT4 h-interleaved
// qdatA[(b*32+qq)*256+h] = (Ta_r0, wv*Ta_r0, Ta_r1, wv*Ta_r1); qdatB same for rows 2,3
// kT4[(b*64+hg)*1024+k]  = (Tb[4hg][k], ..., Tb[4hg+3][k])
__global__ __launch_bounds__(256) void proj_kernel(
    const float* __restrict__ qin, const float* __restrict__ kin,
    const float* __restrict__ Wq, const float* __restrict__ Wk,
    const float* __restrict__ Wv,
    float4* __restrict__ qdatA, float4* __restrict__ qdatB,
    float4* __restrict__ kT4) {
    const int tid = threadIdx.x;
    const int bi  = blockIdx.x;
    __shared__ float tr[NH][9];
    if (bi < NB * 32) {
        const int row0 = bi * 4;
        const float* r0 = qin + row0 * NE;
        float a0 = 0.f, a1 = 0.f, a2 = 0.f, a3 = 0.f;
#pragma unroll 2
        for (int e = 0; e < NE; e += 4) {
            float4 q0 = *(const float4*)(r0 + e);
            float4 q1 = *(const float4*)(r0 + NE + e);
            float4 q2 = *(const float4*)(r0 + 2 * NE + e);
            float4 q3 = *(const float4*)(r0 + 3 * NE + e);
#pragma unroll
            for (int j = 0; j < 4; ++j) {
                float w = Wq[(e + j) * NH + tid];
                a0 = fmaf(((const float*)&q0)[j], w, a0);
                a1 = fmaf(((const float*)&q1)[j], w, a1);
                a2 = fmaf(((const float*)&q2)[j], w, a2);
                a3 = fmaf(((const float*)&q3)[j], w, a3);
            }
        }
        float wv = Wv[tid];
        float t0 = tanh_of(a0), t1 = tanh_of(a1), t2 = tanh_of(a2), t3 = tanh_of(a3);
        qdatA[bi * NH + tid] = make_float4(t0, wv * t0, t1, wv * t1);
        qdatB[bi * NH + tid] = make_float4(t2, wv * t2, t3, wv * t3);
    } else {
        const int kb = bi - NB * 32;
        const int b  = kb >> 7;
        const int k0 = (kb & 127) * 8;
        const float* kr = kin + (b * NK + k0) * NE;
        float acc[8] = {0.f,0.f,0.f,0.f,0.f,0.f,0.f,0.f};
#pragma unroll 2
        for (int e = 0; e < NE; e += 4) {
            float4 kvv[8];
#pragma unroll
            for (int i = 0; i < 8; ++i) kvv[i] = *(const float4*)(kr + i * NE + e);
#pragma unroll
            for (int j = 0; j < 4; ++j) {
                float w = Wk[(e + j) * NH + tid];
#pragma unroll
                for (int i = 0; i < 8; ++i)
                    acc[i] = fmaf(((const float*)&kvv[i])[j], w, acc[i]);
            }
        }
#pragma unroll
        for (int i = 0; i < 8; ++i) tr[tid][i] = tanh_of(acc[i]);
        __syncthreads();
#pragma unroll
        for (int p = 0; p < 2; ++p) {
            int idx2 = p * 256 + tid;
            int hg = idx2 >> 3;
            int kk = idx2 & 7;
            float4 v = make_float4(tr[hg*4+0][kk], tr[hg*4+1][kk],
                                   tr[hg*4+2][kk], tr[hg*4+3][kk]);
            kT4[(b * 64 + hg) * NK + k0 + kk] = v;
        }
    }
}

// ---------------- fused attention: one 256-wide k-chunk per block, 4 q-rows.
// q-side data read as WAVE-UNIFORM global loads (scalar-cache path) -- hot loop
// touches the LDS pipe zero times.
__global__ __launch_bounds__(256) void attn_kernel(
    const float4* __restrict__ qdatA, const float4* __restrict__ qdatB,
    const float4* __restrict__ kT4, const float* __restrict__ V,
    const int* __restrict__ vlen, const float4* __restrict__ Wv4,
    float* __restrict__ part_m, float* __restrict__ part_s,
    float* __restrict__ part_pv) {
    const int tid = threadIdx.x, lane = tid & 63, wid = tid >> 6;
    const int bi = blockIdx.x;
    const int quarter = bi & 3;
    const int b  = (bi >> 2) & 3;
    const int qq = bi >> 4;
    const int vl = vlen[b];
    const int nch = (vl + 255) >> 8;
    const int pidx = (b * 32 + qq) * 4 + quarter;
    float* pm  = part_m + pidx * 4;
    float* ps  = part_s + pidx * 4;
    float* ppv = part_pv + pidx * (4 * NV);

    if (quarter >= nch) {
        if (tid < 4) { pm[tid] = -1e30f; ps[tid] = 0.0f; }
#pragma unroll
        for (int i = 0; i < 4; ++i) ppv[i * 256 + tid] = 0.0f;
        return;
    }

    __shared__ float  pw[4][NH];
    __shared__ float  pvred[4][64 * 17];   // lane stride 17 floats: conflict-free
    __shared__ float  red[4][8];

    const float4* qA = qdatA + (b * 32 + qq) * NH;   // uniform base
    const float4* qB = qdatB + (b * 32 + qq) * NH;

    const int k = quarter * 256 + tid;
    const float4* kp = kT4 + (b * 64) * NK + k;
    float acc0 = 0.f, acc1 = 0.f, acc2 = 0.f, acc3 = 0.f;
#pragma unroll 4
    for (int h4 = 0; h4 < 64; ++h4) {
        float4 kv4 = kp[h4 * NK];        // vector dwordx4, 1KB/wave, L2-resident
        float4 wv4 = Wv4[h4];            // uniform -> scalar cache
#pragma unroll
        for (int j = 0; j < 4; ++j) {
            float kv  = ((const float*)&kv4)[j];
            float wvb = ((const float*)&wv4)[j] * kv;
            float4 qa = qA[h4 * 4 + j];  // uniform -> scalar cache
            float4 qb = qB[h4 * 4 + j];
            acc0 = fmaf(qa.y + wvb, frcp(fmaf(qa.x, kv, 1.0f)), acc0);
            acc1 = fmaf(qa.w + wvb, frcp(fmaf(qa.z, kv, 1.0f)), acc1);
            acc2 = fmaf(qb.y + wvb, frcp(fmaf(qb.x, kv, 1.0f)), acc2);
            acc3 = fmaf(qb.w + wvb, frcp(fmaf(qb.z, kv, 1.0f)), acc3);
        }
    }
    const bool okk = k < vl;
    float s0 = okk ? acc0 : -1e30f;
    float s1 = okk ? acc1 : -1e30f;
    float s2 = okk ? acc2 : -1e30f;
    float s3 = okk ? acc3 : -1e30f;
    float m0 = s0, m1 = s1, m2 = s2, m3 = s3;
#pragma unroll
    for (int d = 32; d >= 1; d >>= 1) {
        m0 = fmaxf(m0, __shfl_xor(m0, d, 64));
        m1 = fmaxf(m1, __shfl_xor(m1, d, 64));
        m2 = fmaxf(m2, __shfl_xor(m2, d, 64));
        m3 = fmaxf(m3, __shfl_xor(m3, d, 64));
    }
    if (lane == 0) { red[wid][0]=m0; red[wid][1]=m1; red[wid][2]=m2; red[wid][3]=m3; }
    __syncthreads();
    m0 = fmaxf(fmaxf(red[0][0], red[1][0]), fmaxf(red[2][0], red[3][0]));
    m1 = fmaxf(fmaxf(red[0][1], red[1][1]), fmaxf(red[2][1], red[3][1]));
    m2 = fmaxf(fmaxf(red[0][2], red[1][2]), fmaxf(red[2][2], red[3][2]));
    m3 = fmaxf(fmaxf(red[0][3], red[1][3]), fmaxf(red[2][3], red[3][3]));
    float p0 = fexp2((s0 - m0) * LOG2E);
    float p1 = fexp2((s1 - m1) * LOG2E);
    float p2 = fexp2((s2 - m2) * LOG2E);
    float p3 = fexp2((s3 - m3) * LOG2E);
    pw[0][tid] = p0; pw[1][tid] = p1; pw[2][tid] = p2; pw[3][tid] = p3;
    float u0 = p0, u1 = p1, u2 = p2, u3 = p3;
#pragma unroll
    for (int d = 32; d >= 1; d >>= 1) {
        u0 += __shfl_xor(u0, d, 64); u1 += __shfl_xor(u1, d, 64);
        u2 += __shfl_xor(u2, d, 64); u3 += __shfl_xor(u3, d, 64);
    }
    if (lane == 0) { red[wid][4]=u0; red[wid][5]=u1; red[wid][6]=u2; red[wid][7]=u3; }
    __syncthreads();
    if (tid == 0) {
        pm[0] = m0; pm[1] = m1; pm[2] = m2; pm[3] = m3;
        ps[0] = red[0][4]+red[1][4]+red[2][4]+red[3][4];
        ps[1] = red[0][5]+red[1][5]+red[2][5]+red[3][5];
        ps[2] = red[0][6]+red[1][6]+red[2][6]+red[3][6];
        ps[3] = red[0][7]+red[1][7]+red[2][7]+red[3][7];
    }
    // PV over this chunk
    const float* Vb = V + (b * NK + quarter * 256) * NV;
    const int v4 = lane * 4;
    float4 o0 = {0,0,0,0}, o1 = {0,0,0,0}, o2 = {0,0,0,0}, o3 = {0,0,0,0};
    for (int kk0 = wid * 4; kk0 < 256; kk0 += 16) {
        float4 pr0 = *(const float4*)&pw[0][kk0];
        float4 pr1 = *(const float4*)&pw[1][kk0];
        float4 pr2 = *(const float4*)&pw[2][kk0];
        float4 pr3 = *(const float4*)&pw[3][kk0];
#pragma unroll
        for (int j = 0; j < 4; ++j) {
            float4 vv = *(const float4*)&Vb[(kk0 + j) * NV + v4];
            float w0 = ((const float*)&pr0)[j], w1 = ((const float*)&pr1)[j];
            float w2 = ((const float*)&pr2)[j], w3 = ((const float*)&pr3)[j];
            o0.x = fmaf(w0, vv.x, o0.x); o0.y = fmaf(w0, vv.y, o0.y);
            o0.z = fmaf(w0, vv.z, o0.z); o0.w = fmaf(w0, vv.w, o0.w);
            o1.x = fmaf(w1, vv.x, o1.x); o1.y = fmaf(w1, vv.y, o1.y);
            o1.z = fmaf(w1, vv.z, o1.z); o1.w = fmaf(w1, vv.w, o1.w);
            o2.x = fmaf(w2, vv.x, o2.x); o2.y = fmaf(w2, vv.y, o2.y);
            o2.z = fmaf(w2, vv.z, o2.z); o2.w = fmaf(w2, vv.w, o2.w);
            o3.x = fmaf(w3, vv.x, o3.x); o3.y = fmaf(w3, vv.y, o3.y);
            o3.z = fmaf(w3, vv.z, o3.z); o3.w = fmaf(w3, vv.w, o3.w);
        }
    }
    {
        float* pd = &pvred[wid][lane * 17];
        *(float4*)(pd + 0)  = o0;
        *(float4*)(pd + 4)  = o1;
        *(float4*)(pd + 8)  = o2;
        *(float4*)(pd + 12) = o3;
    }
    __syncthreads();
    {
        int row = tid >> 6, vg = tid & 63;
        float4 r = {0,0,0,0};
#pragma unroll
        for (int w = 0; w < 4; ++w) {
            float4 t = *(const float4*)&pvred[w][vg * 17 + row * 4];
            r.x += t.x; r.y += t.y; r.z += t.z; r.w += t.w;
        }
        *(float4*)&ppv[row * NV + vg * 4] = r;
    }
}

// ---------------- combine: merge 4 chunk partials per (b,qq), write out
__global__ __launch_bounds__(256) void combine_kernel(
    const float* __restrict__ part_m, const float* __restrict__ part_s,
    const float* __restrict__ part_pv, float* __restrict__ out) {
    const int tid = threadIdx.x;
    const int bi  = blockIdx.x;   // 0..127 = b*32+qq
    const int base = bi * 4;
#pragma unroll
    for (int i = 0; i < 4; ++i) {
        float m[4], s[4];
#pragma unroll
        for (int q = 0; q < 4; ++q) {
            m[q] = part_m[(base + q) * 4 + i];
            s[q] = part_s[(base + q) * 4 + i];
        }
        float M = fmaxf(fmaxf(m[0], m[1]), fmaxf(m[2], m[3]));
        float w[4], S = 0.f;
#pragma unroll
        for (int q = 0; q < 4; ++q) {
            w[q] = fexp2((m[q] - M) * LOG2E);
            S = fmaf(s[q], w[q], S);
        }
        float o = 0.f;
#pragma unroll
        for (int q = 0; q < 4; ++q)
            o = fmaf(part_pv[((base + q) * 4 + i) * NV + tid], w[q], o);
        out[(base + i) * NV + tid] = o * frcp(S);
    }
}

extern "C" void kernel_launch(void* const* d_in, const int* in_sizes, int n_in,
                              void* d_out, int out_size, void* d_ws, size_t ws_size,
                              hipStream_t stream) {
    const float* queries = (const float*)d_in[0];
    const float* keys    = (const float*)d_in[1];
    const float* values  = (const float*)d_in[2];
    const int*   vlens   = (const int*)  d_in[3];
    const float* Wq      = (const float*)d_in[4];
    const float* Wk      = (const float*)d_in[5];
    const float* Wv      = (const float*)d_in[6];
    float* out = (float*)d_out;

    float4* qdatA  = (float4*)d_ws;                  // 32768 float4 (512 KB)
    float4* qdatB  = qdatA + NB * 32 * NH;           // 32768 float4 (512 KB)
    float4* kT4    = qdatB + NB * 32 * NH;           // 262144 float4 (4 MB)
    float*  part_m = (float*)(kT4 + NB * 64 * NK);   // 2048 floats
    float*  part_s = part_m + 2048;                  // 2048 floats
    float*  part_pv = part_s + 2048;                 // 524288 floats (2 MB)

    proj_kernel   <<<dim3(640), dim3(256), 0, stream>>>(queries, keys, Wq, Wk, Wv,
                                                        qdatA, qdatB, kT4);
    attn_kernel   <<<dim3(512), dim3(256), 0, stream>>>(qdatA, qdatB, kT4, values,
                                                        vlens, (const float4*)Wv,
                                                        part_m, part_s, part_pv);
    combine_kernel<<<dim3(128), dim3(256), 0, stream>>>(part_m, part_s, part_pv, out);
}